// Round 4
// baseline (406.738 us; speedup 1.0000x reference)
//
#include <hip/hip_runtime.h>
#include <cstdint>

// Grid-to-mesh GEMM: X[16384, 4096] (fp32, cast to bf16) x W[4096, 176-pad] (bf16)
// -> out[B=32][N=162][C=512] fp32.
constexpr int KDIM = 4096;          // H*W
constexpr int NDIM = 162;
constexpr int NPAD = 176;           // 11 tiles of 16
constexpr int NT   = 11;
constexpr int CDIM = 512;
constexpr int BM   = 64;            // rows per block
constexpr int BK   = 128;           // K per chunk
constexpr int NCHUNK = KDIM / BK;   // 32
constexpr int WBYTES = 4 * NT * 64 * 16;   // packed-W bytes per chunk = 45056
constexpr int TOTAL_PACK = KDIM * NPAD;    // 720896 bf16 elements
constexpr int TSTRIDE = 177;        // epilogue tile stride (bank-conflict-free)

typedef float f32x4 __attribute__((ext_vector_type(4)));
typedef short s16x8 __attribute__((ext_vector_type(8)));

__device__ __forceinline__ ushort f2bf(float f) {
  uint32_t u = __builtin_bit_cast(uint32_t, f);
  u += 0x7FFFu + ((u >> 16) & 1u);          // round-to-nearest-even
  return (ushort)(u >> 16);
}

__device__ __forceinline__ void gll16(const void* g, void* l) {
  __builtin_amdgcn_global_load_lds(
      (const __attribute__((address_space(1))) uint32_t*)(uintptr_t)g,
      (__attribute__((address_space(3))) uint32_t*)(uintptr_t)l,
      16, 0, 0);
}

// ---- prep: pack weight [H,W,N] fp32 -> bf16 fragment-image layout ----
// flat bf16 index = (((kst*11 + tn)*64 + lane)*8 + e)
//   k = kst*32 + (lane>>4)*8 + e ; n = tn*16 + (lane&15) (zero-pad n>=162)
__global__ void pack_w_kernel(const float* __restrict__ w, ushort* __restrict__ wp) {
  int idx = blockIdx.x * 512 + threadIdx.x;     // [0, 720896)
  int e    = idx & 7;
  int lane = (idx >> 3) & 63;
  int t3   = idx >> 9;                           // [0, 1408)
  int tn   = t3 % NT;
  int kst  = t3 / NT;                            // [0, 128)
  int k = kst * 32 + (lane >> 4) * 8 + e;
  int n = tn * 16 + (lane & 15);
  float v = (n < NDIM) ? w[k * NDIM + n] : 0.0f;
  wp[idx] = f2bf(v);
}

__device__ __forceinline__ void stage_chunk(const ushort* wp, char* smem_c,
                                            int buf, int kc, int wid, int lane) {
  const char* gbase = (const char*)wp + (size_t)kc * WBYTES;
  char* lbase = smem_c + buf * WBYTES;
#pragma unroll
  for (int r = 0; r < 6; ++r) {
    int rr = r * 8 + wid;                        // wave-rounds of 1 KiB; 44 total
    if (rr < 44) gll16(gbase + rr * 1024 + (size_t)lane * 16, lbase + rr * 1024);
  }
}

__global__ __launch_bounds__(512, 2) void fmap_gemm(
    const float* __restrict__ x, const ushort* __restrict__ wp,
    float* __restrict__ out) {
  __shared__ char smem[2 * WBYTES];              // 90112 B static (1 block/CU)
  const int tid  = threadIdx.x;
  const int lane = tid & 63;
  const int wid  = tid >> 6;                     // 0..7
  const int wm   = wid & 3;                      // m-subtile (16 rows)
  const int kh   = wid >> 2;                     // K-half

  const int m0  = blockIdx.x * BM;
  const int row = m0 + wm * 16 + (lane & 15);
  const int g   = lane >> 4;
  const int ks0 = kh * 2;                        // this wave's mfma k-steps: ks0, ks0+1

  const float* xrow = x + (size_t)row * KDIM + g * 8;

  f32x4 acc[NT];
#pragma unroll
  for (int t = 0; t < NT; ++t) acc[t] = f32x4{0.f, 0.f, 0.f, 0.f};

  // ---- prologue: stage chunk 0, load A(chunk 0) ----
  stage_chunk(wp, smem, 0, 0, wid, lane);
  float4 a_c[4];
  {
    const float* pb = xrow + ks0 * 32;
    a_c[0] = ((const float4*)pb)[0];
    a_c[1] = ((const float4*)pb)[1];
    a_c[2] = ((const float4*)(pb + 32))[0];
    a_c[3] = ((const float4*)(pb + 32))[1];
  }

  for (int kc = 0; kc < NCHUNK; ++kc) {
    const int cur = kc & 1, nxt = cur ^ 1;
    const bool has_next = (kc + 1 < NCHUNK);

    if (has_next) {
      stage_chunk(wp, smem, nxt, kc + 1, wid, lane);
      // Drain current chunk's staging (+A); leave only the 6/5 newest (next-chunk) in flight.
      if (wid < 4) asm volatile("s_waitcnt vmcnt(6)" ::: "memory");
      else         asm volatile("s_waitcnt vmcnt(5)" ::: "memory");
    } else {
      asm volatile("s_waitcnt vmcnt(0)" ::: "memory");
    }
    __syncthreads();                             // staging of buf[cur] visible to all

    float4 a_n[4];
    if (has_next) {                              // A prefetch for next chunk (kept in flight)
      const float* pb = xrow + (kc + 1) * BK + ks0 * 32;
      a_n[0] = ((const float4*)pb)[0];
      a_n[1] = ((const float4*)pb)[1];
      a_n[2] = ((const float4*)(pb + 32))[0];
      a_n[3] = ((const float4*)(pb + 32))[1];
    }

    // convert current A fp32 -> bf16 fragments
    s16x8 af0, af1;
    af0[0] = (short)f2bf(a_c[0].x); af0[1] = (short)f2bf(a_c[0].y);
    af0[2] = (short)f2bf(a_c[0].z); af0[3] = (short)f2bf(a_c[0].w);
    af0[4] = (short)f2bf(a_c[1].x); af0[5] = (short)f2bf(a_c[1].y);
    af0[6] = (short)f2bf(a_c[1].z); af0[7] = (short)f2bf(a_c[1].w);
    af1[0] = (short)f2bf(a_c[2].x); af1[1] = (short)f2bf(a_c[2].y);
    af1[2] = (short)f2bf(a_c[2].z); af1[3] = (short)f2bf(a_c[2].w);
    af1[4] = (short)f2bf(a_c[3].x); af1[5] = (short)f2bf(a_c[3].y);
    af1[6] = (short)f2bf(a_c[3].z); af1[7] = (short)f2bf(a_c[3].w);

    const char* bb = smem + cur * WBYTES + (size_t)lane * 16;
#pragma unroll
    for (int t = 0; t < NT; ++t) {
      s16x8 b0 = *(const s16x8*)(bb + (size_t)((ks0 * NT + t) * 64) * 16);
      s16x8 b1 = *(const s16x8*)(bb + (size_t)(((ks0 + 1) * NT + t) * 64) * 16);
      acc[t] = __builtin_amdgcn_mfma_f32_16x16x32_bf16(af0, b0, acc[t], 0, 0, 0);
      acc[t] = __builtin_amdgcn_mfma_f32_16x16x32_bf16(af1, b1, acc[t], 0, 0, 0);
    }
    __syncthreads();                             // all reads of buf[cur] done

#pragma unroll
    for (int q = 0; q < 4; ++q) a_c[q] = a_n[q];
  }

  // ---- epilogue: K-half reduction + transpose via LDS, coalesced writes ----
  float* tile = (float*)smem;                    // [64][TSTRIDE] fp32 = 45312 B
  const int ncol  = lane & 15;
  const int rbase = wm * 16 + g * 4;             // D layout: col=lane&15, row=(lane>>4)*4+j
  if (kh == 0) {
#pragma unroll
    for (int t = 0; t < NT; ++t)
#pragma unroll
      for (int j = 0; j < 4; ++j)
        tile[(rbase + j) * TSTRIDE + t * 16 + ncol] = acc[t][j];
  }
  __syncthreads();
  if (kh == 1) {
#pragma unroll
    for (int t = 0; t < NT; ++t)
#pragma unroll
      for (int j = 0; j < 4; ++j)
        tile[(rbase + j) * TSTRIDE + t * 16 + ncol] += acc[t][j];
  }
  __syncthreads();

  const int bidx = m0 >> 9;                      // batch
  const int c0   = m0 & 511;                     // channel base
  float* obase = out + (size_t)bidx * (NDIM * CDIM) + c0;
#pragma unroll
  for (int r = 0; r < 6; ++r) {
    int idx = r * 512 + tid;
    if (idx < NDIM * 16) {                       // 162 n * 16 float4-groups
      int n  = idx >> 4;
      int cq = idx & 15;
      float4 v;
      v.x = tile[(cq * 4 + 0) * TSTRIDE + n];
      v.y = tile[(cq * 4 + 1) * TSTRIDE + n];
      v.z = tile[(cq * 4 + 2) * TSTRIDE + n];
      v.w = tile[(cq * 4 + 3) * TSTRIDE + n];
      *(float4*)(obase + n * CDIM + cq * 4) = v;
    }
  }
}

extern "C" void kernel_launch(void* const* d_in, const int* in_sizes, int n_in,
                              void* d_out, int out_size, void* d_ws, size_t ws_size,
                              hipStream_t stream) {
  const float* x = (const float*)d_in[0];
  const float* w = (const float*)d_in[1];
  float* outp    = (float*)d_out;
  ushort* wp     = (ushort*)d_ws;                // 720896 * 2 B = 1.44 MB packed weight

  pack_w_kernel<<<TOTAL_PACK / 512, 512, 0, stream>>>(w, wp);
  fmap_gemm<<<(32 * CDIM) / BM, 512, 0, stream>>>(x, wp, outp);
}

// Round 5
// 396.397 us; speedup vs baseline: 1.0261x; 1.0261x over previous
//
#include <hip/hip_runtime.h>
#include <cstdint>

// Grid-to-mesh GEMM: X[16384, 4096] (fp32, cast to bf16) x W[4096, 176-pad] (bf16)
// -> out[B=32][N=162][C=512] fp32.
constexpr int KDIM = 4096;          // H*W
constexpr int NDIM = 162;
constexpr int NPAD = 176;           // 11 tiles of 16
constexpr int NT   = 11;
constexpr int CDIM = 512;
constexpr int BM   = 64;            // rows per block
constexpr int BK   = 64;            // K per chunk (2 k-steps of 32)
constexpr int NCHUNK = KDIM / BK;   // 64
constexpr int WBYTES = 2 * NT * 64 * 16;   // packed-W bytes per chunk = 22528
constexpr int TOTAL_PACK = KDIM * NPAD;    // 720896 bf16 elements
constexpr int TSTRIDE = 177;        // epilogue tile stride (bank-conflict-free)
constexpr int SMEM_BYTES = 64 * TSTRIDE * 4;  // 45312 >= 2*WBYTES (45056)

typedef float f32x4 __attribute__((ext_vector_type(4)));
typedef short s16x8 __attribute__((ext_vector_type(8)));

__device__ __forceinline__ ushort f2bf(float f) {
  uint32_t u = __builtin_bit_cast(uint32_t, f);
  u += 0x7FFFu + ((u >> 16) & 1u);          // round-to-nearest-even
  return (ushort)(u >> 16);
}

__device__ __forceinline__ void gll16(const void* g, void* l) {
  __builtin_amdgcn_global_load_lds(
      (const __attribute__((address_space(1))) uint32_t*)(uintptr_t)g,
      (__attribute__((address_space(3))) uint32_t*)(uintptr_t)l,
      16, 0, 0);
}

// ---- prep: pack weight [H,W,N] fp32 -> bf16 fragment-image layout ----
// flat bf16 index = (((kst*11 + tn)*64 + lane)*8 + e)
//   k = kst*32 + (lane>>4)*8 + e ; n = tn*16 + (lane&15) (zero-pad n>=162)
__global__ void pack_w_kernel(const float* __restrict__ w, ushort* __restrict__ wp) {
  int idx = blockIdx.x * 512 + threadIdx.x;     // [0, 720896)
  int e    = idx & 7;
  int lane = (idx >> 3) & 63;
  int t3   = idx >> 9;                           // [0, 1408)
  int tn   = t3 % NT;
  int kst  = t3 / NT;                            // [0, 128)
  int k = kst * 32 + (lane >> 4) * 8 + e;
  int n = tn * 16 + (lane & 15);
  float v = (n < NDIM) ? w[k * NDIM + n] : 0.0f;
  wp[idx] = f2bf(v);
}

__device__ __forceinline__ void stage_chunk(const ushort* wp, char* smem_c,
                                            int buf, int kc, int wid, int lane) {
  const char* gbase = (const char*)wp + (size_t)kc * WBYTES;
  char* lbase = smem_c + buf * WBYTES;
#pragma unroll
  for (int r = 0; r < 3; ++r) {
    int rr = r * 8 + wid;                        // wave-rounds of 1 KiB; 22 total
    if (rr < 22) gll16(gbase + rr * 1024 + (size_t)lane * 16, lbase + rr * 1024);
  }
}

__global__ __launch_bounds__(512, 4) void fmap_gemm(
    const float* __restrict__ x, const ushort* __restrict__ wp,
    float* __restrict__ out) {
  __shared__ char smem[SMEM_BYTES];              // 45312 B -> 2-3 blocks/CU
  const int tid  = threadIdx.x;
  const int lane = tid & 63;
  const int wid  = tid >> 6;                     // 0..7
  const int wm   = wid & 3;                      // m-subtile (16 rows)
  const int kh   = wid >> 2;                     // k-step within chunk (0/1)

  const int m0  = blockIdx.x * BM;
  const int row = m0 + wm * 16 + (lane & 15);
  const int g   = lane >> 4;

  const float* xrow = x + (size_t)row * KDIM + g * 8 + kh * 32;

  f32x4 acc[NT];
#pragma unroll
  for (int t = 0; t < NT; ++t) acc[t] = f32x4{0.f, 0.f, 0.f, 0.f};

  // ---- prologue: stage chunk 0, load A(chunk 0), one barrier ----
  stage_chunk(wp, smem, 0, 0, wid, lane);
  float4 a_c0, a_c1;
  a_c0 = ((const float4*)xrow)[0];
  a_c1 = ((const float4*)xrow)[1];
  __syncthreads();                               // drain: buf0 + a_c visible

  for (int kc = 0; kc < NCHUNK; ++kc) {
    const int cur = kc & 1;
    const bool has_next = (kc + 1 < NCHUNK);

    // issue next-chunk staging + A prefetch FIRST; the end-of-iter barrier's
    // implicit vmcnt(0) drain completes them after this chunk's compute.
    float4 a_n0, a_n1;
    if (has_next) {
      stage_chunk(wp, smem, cur ^ 1, kc + 1, wid, lane);
      const float* pb = xrow + (kc + 1) * BK;
      a_n0 = ((const float4*)pb)[0];
      a_n1 = ((const float4*)pb)[1];
    }

    // convert current A fp32 -> bf16 fragment (8 elems, one k-step of 32)
    s16x8 af;
    af[0] = (short)f2bf(a_c0.x); af[1] = (short)f2bf(a_c0.y);
    af[2] = (short)f2bf(a_c0.z); af[3] = (short)f2bf(a_c0.w);
    af[4] = (short)f2bf(a_c1.x); af[5] = (short)f2bf(a_c1.y);
    af[6] = (short)f2bf(a_c1.z); af[7] = (short)f2bf(a_c1.w);

    const char* bb = smem + cur * WBYTES + (size_t)lane * 16;
#pragma unroll
    for (int t = 0; t < NT; ++t) {
      s16x8 b0 = *(const s16x8*)(bb + (size_t)((kh * NT + t) * 64) * 16);
      acc[t] = __builtin_amdgcn_mfma_f32_16x16x32_bf16(af, b0, acc[t], 0, 0, 0);
    }

    __syncthreads();   // (a) all reads of buf[cur] done -> safe to overwrite
                       // (b) implicit full drain -> stage(next)+a_n complete
    a_c0 = a_n0; a_c1 = a_n1;
  }

  // ---- epilogue: k-step reduction + transpose via LDS, coalesced writes ----
  float* tile = (float*)smem;                    // [64][TSTRIDE] fp32 = 45312 B
  const int ncol  = lane & 15;
  const int rbase = wm * 16 + g * 4;             // D layout: col=lane&15, row=(lane>>4)*4+j
  if (kh == 0) {
#pragma unroll
    for (int t = 0; t < NT; ++t)
#pragma unroll
      for (int j = 0; j < 4; ++j)
        tile[(rbase + j) * TSTRIDE + t * 16 + ncol] = acc[t][j];
  }
  __syncthreads();
  if (kh == 1) {
#pragma unroll
    for (int t = 0; t < NT; ++t)
#pragma unroll
      for (int j = 0; j < 4; ++j)
        tile[(rbase + j) * TSTRIDE + t * 16 + ncol] += acc[t][j];
  }
  __syncthreads();

  const int bidx = m0 >> 9;                      // batch
  const int c0   = m0 & 511;                     // channel base
  float* obase = out + (size_t)bidx * (NDIM * CDIM) + c0;
#pragma unroll
  for (int r = 0; r < 6; ++r) {
    int idx = r * 512 + tid;
    if (idx < NDIM * 16) {                       // 162 n * 16 float4-groups
      int n  = idx >> 4;
      int cq = idx & 15;
      float4 v;
      v.x = tile[(cq * 4 + 0) * TSTRIDE + n];
      v.y = tile[(cq * 4 + 1) * TSTRIDE + n];
      v.z = tile[(cq * 4 + 2) * TSTRIDE + n];
      v.w = tile[(cq * 4 + 3) * TSTRIDE + n];
      *(float4*)(obase + n * CDIM + cq * 4) = v;
    }
  }
}

extern "C" void kernel_launch(void* const* d_in, const int* in_sizes, int n_in,
                              void* d_out, int out_size, void* d_ws, size_t ws_size,
                              hipStream_t stream) {
  const float* x = (const float*)d_in[0];
  const float* w = (const float*)d_in[1];
  float* outp    = (float*)d_out;
  ushort* wp     = (ushort*)d_ws;                // 720896 * 2 B = 1.44 MB packed weight

  pack_w_kernel<<<TOTAL_PACK / 512, 512, 0, stream>>>(w, wp);
  fmap_gemm<<<(32 * CDIM) / BM, 512, 0, stream>>>(x, wp, outp);
}